// Round 13
// baseline (103.080 us; speedup 1.0000x reference)
//
#include <hip/hip_runtime.h>
#include <math.h>

#define B 16
#define E 64
#define H 8
#define L 2048
#define M 64
#define PLANE (B*H*E*M)   // 524288 float2 per spectral plane

// exact 32-pt DFT twiddles: CS32[j]=cos(pi j/16), SN32[j]=sin(pi j/16)
constexpr float CS32[32] = {
     1.0f,                    0.9807852804032304f,   0.9238795325112868f,   0.8314696123025452f,
     0.7071067811865476f,     0.5555702330196022f,   0.3826834323650898f,   0.1950903220161283f,
     0.0f,                   -0.1950903220161283f,  -0.3826834323650898f,  -0.5555702330196022f,
    -0.7071067811865476f,    -0.8314696123025452f,  -0.9238795325112868f,  -0.9807852804032304f,
    -1.0f,                   -0.9807852804032304f,  -0.9238795325112868f,  -0.8314696123025452f,
    -0.7071067811865476f,    -0.5555702330196022f,  -0.3826834323650898f,  -0.1950903220161283f,
     0.0f,                    0.1950903220161283f,   0.3826834323650898f,   0.5555702330196022f,
     0.7071067811865476f,     0.8314696123025452f,   0.9238795325112868f,   0.9807852804032304f
};
constexpr float SN32[32] = {
     0.0f,                    0.1950903220161283f,   0.3826834323650898f,   0.5555702330196022f,
     0.7071067811865476f,     0.8314696123025452f,   0.9238795325112868f,   0.9807852804032304f,
     1.0f,                    0.9807852804032304f,   0.9238795325112868f,   0.8314696123025452f,
     0.7071067811865476f,     0.5555702330196022f,   0.3826834323650898f,   0.1950903220161283f,
     0.0f,                   -0.1950903220161283f,  -0.3826834323650898f,  -0.5555702330196022f,
    -0.7071067811865476f,    -0.8314696123025452f,  -0.9238795325112868f,  -0.9807852804032304f,
    -1.0f,                   -0.9807852804032304f,  -0.9238795325112868f,  -0.8314696123025452f,
    -0.7071067811865476f,    -0.5555702330196022f,  -0.3826834323650898f,  -0.1950903220161283f
};

__device__ inline void ctanhf_stable(float x, float y, float& re, float& im) {
    float ax = fabsf(x);
    if (ax > 11.0f) { re = copysignf(1.0f, x); im = 0.0f; return; }
    float t    = tanf(y);
    float beta = 1.0f + t * t;
    float s    = sinhf(x);
    float rho  = sqrtf(1.0f + s * s);
    float den  = 1.0f + beta * s * s;
    re = (beta * rho * s) / den;
    im = t / den;
}

// ---------------------------------------------------------------------------
// Prep kernel: W transpose (all 512 blocks) + quarter twiddle table (blocks
// 0..3). Wt: w_re/w_im [H][E][O][M] -> float2 [H][m][E][O].
// Tg[r*32+m] = e^{-i pi m r/1024}, r<32, m<32.
// ---------------------------------------------------------------------------
__global__ __launch_bounds__(256) void k_wtrans(const float* __restrict__ wre,
                                                const float* __restrict__ wim,
                                                float2* __restrict__ Wt,
                                                float2* __restrict__ Tgo)
{
    __shared__ float tre[64][65], tim[64][65];
    int h  = blockIdx.x >> 6, rt = blockIdx.x & 63;
    int tid = threadIdx.x;

    int gidx = blockIdx.x * 256 + tid;
    if (gidx < 1024) {
        int r = gidx >> 5, m = gidx & 31;
        double a = -3.14159265358979323846 * (double)(m * r) / 1024.0;
        Tgo[gidx] = make_float2((float)cos(a), (float)sin(a));
    }

    int x = tid & 63, r4 = tid >> 6;
    const size_t base = ((size_t)h * 4096 + (size_t)rt * 64) * 64;
    #pragma unroll
    for (int j = 0; j < 16; ++j) {
        int row = j * 4 + r4;
        tre[row][x] = wre[base + (size_t)row * 64 + x];
        tim[row][x] = wim[base + (size_t)row * 64 + x];
    }
    __syncthreads();

    int row = tid & 63, x4 = tid >> 6;
    #pragma unroll
    for (int j = 0; j < 16; ++j) {
        int xx = j * 4 + x4;
        Wt[((size_t)h * 64 + xx) * 4096 + (size_t)rt * 64 + row] =
            make_float2(tre[row][xx], tim[row][xx]);
    }
}

// ---------------------------------------------------------------------------
// Forward DFT, 4 rows/block, wave-independent, LDS = exactly 40,960 B
// -> 4 blocks/CU (16 waves), the first real occupancy increase.
// Y compact: 17 re + 15 im = 32 floats/row (Yim[0]=Yim[16]=0 exactly),
// XOR-swizzled j^(r&31): conflict-free writes, broadcast reads.
// Quarter twiddle table [32][32]; m+32 columns built as tb*Cg[rp], Cg in
// registers (lane l holds Cg[l&31], fetched via __shfl(.,rp) -> readlane).
// Half-1 post-rotates by its own +-Cg[mlow] (lane&31 == mlow); combine via
// __shfl_xor(.,32). One barrier total (table staging).
// ---------------------------------------------------------------------------
__global__ __launch_bounds__(256) void k_dft(const float* __restrict__ q,
                                             const float* __restrict__ k,
                                             const float2* __restrict__ Tg,
                                             float2* __restrict__ Xq,
                                             float2* __restrict__ Xk)
{
    __shared__ float  Smem[4][2048];    // 32,768 B compact swizzled Y
    __shared__ float2 Tsm[32][32];      //  8,192 B  (total 40,960 -> 4/CU)

    int tid  = threadIdx.x;
    int rloc = tid >> 6;
    int lane = tid & 63;
    int rid  = blockIdx.x * 4 + rloc;                  // 0..16383
    int tensor = rid >> 13;
    int r8 = rid & 8191;
    int b = r8 >> 9, h = (r8 >> 6) & 7, e = r8 & 63;

    // stage quarter table (8 KB from L2), one barrier total
    #pragma unroll
    for (int j = 0; j < 4; ++j) ((float2*)Tsm)[tid + 256 * j] = Tg[tid + 256 * j];
    __syncthreads();

    // per-lane Cg: lane l holds e^{-i pi (l&31)/32}
    float cgr, cgi;
    sincosf(-9.8174770424681038e-2f * (float)(lane & 31), &cgi, &cgr);

    const float* src = (tensor ? k : q) + (((size_t)(b * E + e) * H + h) * L) + lane;
    float xs[32];
    #pragma unroll
    for (int i = 0; i < 32; ++i) xs[i] = src[i * 64];

    // phase 1: 32-pt real DFT, compact swizzled store (intra-wave region)
    float s_[16], d_[16];
    #pragma unroll
    for (int i = 1; i <= 15; ++i) { s_[i] = xs[i] + xs[32 - i]; d_[i] = xs[i] - xs[32 - i]; }

    float* Wf = &Smem[rloc][0];
    int rsw = lane & 31;
    #pragma unroll
    for (int f = 0; f <= 16; ++f) {
        float ar = xs[0] + ((f & 1) ? -xs[16] : xs[16]);
        float ai = 0.f;
        #pragma unroll
        for (int i = 1; i <= 15; ++i) {
            ar = fmaf(s_[i], CS32[(f * i) & 31], ar);
            ai = fmaf(d_[i], SN32[(f * i) & 31], ai);
        }
        Wf[lane * 32 + (f ^ rsw)] = ar;
        if (f >= 1 && f <= 15) Wf[lane * 32 + ((16 + f) ^ rsw)] = -ai;
    }

    // phase 2: lane = (half, mlow)
    int mlow = lane & 31;
    int half = lane >> 5;
    int fi   = (mlow <= 16) ? mlow : 32 - mlow;
    float sgn = (mlow <= 16) ? 1.f : -1.f;
    int  noim = (fi == 0) | (fi == 16);
    int  jim  = noim ? 16 : (16 + fi);
    float imk = noim ? 0.f : sgn;

    float ar0 = 0.f, ai0 = 0.f, ar1 = 0.f, ai1 = 0.f;
    int rbase = half * 32;
    #pragma unroll
    for (int rb = 0; rb < 4; ++rb) {
        float2 tb[8]; float cbr[8], cbi[8], yr[8], yi[8];
        #pragma unroll
        for (int j = 0; j < 8; ++j) {
            int rp = rb * 8 + j;
            int r  = rbase + rp;
            tb[j]  = Tsm[rp][mlow];
            cbr[j] = __shfl(cgr, rp);
            cbi[j] = __shfl(cgi, rp);
            yr[j]  = Wf[r * 32 + (fi ^ rp)];
            yi[j]  = imk * Wf[r * 32 + (jim ^ rp)];
        }
        #pragma unroll
        for (int j = 0; j < 8; ++j) {
            ar0 = fmaf(yr[j], tb[j].x, ar0); ar0 = fmaf(-yi[j], tb[j].y, ar0);
            ai0 = fmaf(yr[j], tb[j].y, ai0); ai0 = fmaf( yi[j], tb[j].x, ai0);
            float t2r = tb[j].x * cbr[j] - tb[j].y * cbi[j];   // T[rp][mlow+32]
            float t2i = tb[j].x * cbi[j] + tb[j].y * cbr[j];
            ar1 = fmaf(yr[j], t2r, ar1); ar1 = fmaf(-yi[j], t2i, ar1);
            ai1 = fmaf(yr[j], t2i, ai1); ai1 = fmaf( yi[j], t2r, ai1);
        }
    }

    if (half) {
        // T[32+rp][m] = T[rp][m]*Cg[mlow] (m=mlow); extra -1 for m=mlow+32
        float t;
        t   = ar0 * cgr - ai0 * cgi;
        ai0 = ar0 * cgi + ai0 * cgr;  ar0 = t;
        t   = ar1 * cgr - ai1 * cgi;
        ai1 = ar1 * cgi + ai1 * cgr;  ar1 = t;
        ar1 = -ar1; ai1 = -ai1;
    }
    ar0 += __shfl_xor(ar0, 32);  ai0 += __shfl_xor(ai0, 32);
    ar1 += __shfl_xor(ar1, 32);  ai1 += __shfl_xor(ai1, 32);

    float2* dst = (tensor ? Xk : Xq) + ((size_t)(b * H + h) * E + e) * M;
    if (!half) dst[mlow]      = make_float2(ar0, ai0);
    else       dst[mlow + 32] = make_float2(ar1, ai1);
}

// ---------------------------------------------------------------------------
// Per (bh, x-quarter): S = tanh(Q^T K) (fp32 accum), then
// U[h][x][b][e] = sum_y S[x][y] K[e][y].  Grid 512 -> 2 blocks/CU.
// ---------------------------------------------------------------------------
__global__ __launch_bounds__(256) void k_mid(const float2* __restrict__ Xq,
                                             const float2* __restrict__ Xk,
                                             float2* __restrict__ U)
{
    __shared__ float Qre[64][16], Qim[64][16];   // [e][xl]; becomes S [y][xl]
    __shared__ float Kre[64][65], Kim[64][65];   // [e][m], padded

    int bh = blockIdx.x >> 2;
    int xh = (blockIdx.x & 3) * 16;
    int b  = bh >> 3, h = bh & 7;
    int tid = threadIdx.x;
    const float2* xq = Xq + (size_t)bh * 4096;
    const float2* xk = Xk + (size_t)bh * 4096;

    #pragma unroll
    for (int j = 0; j < 4; ++j) {
        int idx = tid + 256 * j;                 // 1024 = 64e * 16x
        int e = idx >> 4, xl = idx & 15;
        float2 v = xq[(e << 6) + xh + xl];
        Qre[e][xl] = v.x; Qim[e][xl] = v.y;
    }
    #pragma unroll
    for (int j = 0; j < 16; ++j) {
        int idx = tid + 256 * j;                 // 4096 = 64e * 64m
        int e = idx >> 6, mm = idx & 63;
        float2 v = xk[idx];
        Kre[e][mm] = v.x; Kim[e][mm] = v.y;
    }
    __syncthreads();

    int x  = tid & 15;
    int y0 = (tid >> 4) * 4;
    float ar[4], ai[4];
    #pragma unroll
    for (int j = 0; j < 4; ++j) { ar[j] = 0.f; ai[j] = 0.f; }

    for (int e = 0; e < 64; ++e) {
        float qr = Qre[e][x], qi = Qim[e][x];
        #pragma unroll
        for (int j = 0; j < 4; ++j) {
            float kr = Kre[e][y0 + j], ki = Kim[e][y0 + j];
            ar[j] = fmaf(qr, kr, ar[j]); ar[j] = fmaf(-qi, ki, ar[j]);
            ai[j] = fmaf(qr, ki, ai[j]); ai[j] = fmaf( qi, kr, ai[j]);
        }
    }
    float trj[4], tij[4];
    #pragma unroll
    for (int j = 0; j < 4; ++j) ctanhf_stable(ar[j], ai[j], trj[j], tij[j]);

    __syncthreads();
    #pragma unroll
    for (int j = 0; j < 4; ++j) { Qre[y0 + j][x] = trj[j]; Qim[y0 + j][x] = tij[j]; }
    __syncthreads();

    int eL    = tid & 63;
    int xslot = tid >> 6;                        // 0..3
    float ur[4], ui[4];
    #pragma unroll
    for (int j = 0; j < 4; ++j) { ur[j] = 0.f; ui[j] = 0.f; }

    for (int y = 0; y < 64; ++y) {
        float kr = Kre[eL][y], ki = Kim[eL][y];
        #pragma unroll
        for (int xp = 0; xp < 4; ++xp) {
            int xx = xp * 4 + xslot;
            float sr = Qre[y][xx], si = Qim[y][xx];
            ur[xp] += sr * kr - si * ki;
            ui[xp] += sr * ki + si * kr;
        }
    }
    #pragma unroll
    for (int xp = 0; xp < 4; ++xp) {
        int xx = xp * 4 + xslot;
        U[(((size_t)h * 64 + xh + xx) * 16 + b) * 64 + eL] = make_float2(ur[xp], ui[xp]);
    }
}

// ---------------------------------------------------------------------------
// Per (h, mode x): R[b][o] = sum_e U[b][e] * Wt[e][o]
// ---------------------------------------------------------------------------
__global__ __launch_bounds__(256) void k_wmix(const float2* __restrict__ U,   // [h][x][b][e]
                                              const float2* __restrict__ Wt,  // [h][x][e][o]
                                              float2* __restrict__ R)
{
    __shared__ float2 Usm[16][64];
    __shared__ float2 Wsm[64][64];

    int h = blockIdx.x >> 6, x = blockIdx.x & 63;
    int tid = threadIdx.x;

    const float2* usrc = U  + ((size_t)h * 64 + x) * 1024;
    #pragma unroll
    for (int j = 0; j < 4; ++j) {
        int idx = tid + 256 * j;
        ((float2*)Usm)[idx] = usrc[idx];
    }
    const float2* wsrc = Wt + ((size_t)h * 64 + x) * 4096;
    #pragma unroll
    for (int j = 0; j < 16; ++j) {
        int idx = tid + 256 * j;
        ((float2*)Wsm)[idx] = wsrc[idx];
    }
    __syncthreads();

    int o = tid & 63, b0 = tid >> 6;
    float rr[4], ri[4];
    #pragma unroll
    for (int j = 0; j < 4; ++j) { rr[j] = 0.f; ri[j] = 0.f; }

    for (int e = 0; e < 64; ++e) {
        float2 w = Wsm[e][o];
        #pragma unroll
        for (int j = 0; j < 4; ++j) {
            float2 u = Usm[b0 + 4 * j][e];
            rr[j] += u.x * w.x - u.y * w.y;
            ri[j] += u.x * w.y + u.y * w.x;
        }
    }
    #pragma unroll
    for (int j = 0; j < 4; ++j) {
        int b = b0 + 4 * j;
        R[((size_t)(b * H + h) * 64 + o) * 64 + x] = make_float2(rr[j], ri[j]);
    }
}

// ---------------------------------------------------------------------------
// irFFT, 4 rows per block, barrier-free (Fsh exchange is intra-wave).
// ---------------------------------------------------------------------------
__global__ __launch_bounds__(256) void k_irfft(const float2* __restrict__ R,
                                               float* __restrict__ out)
{
    __shared__ float2 Fsh[4][64];
    int rloc = threadIdx.x >> 6;
    int r    = threadIdx.x & 63;
    int bho  = blockIdx.x * 4 + rloc;
    int o  = bho & 63, bh = bho >> 6;
    int h  = bh & 7,   b  = bh >> 3;

    Fsh[rloc][r] = R[(size_t)bho * 64 + r];   // wave-private row; no barrier

    float sr_, cr_;
    sincosf(3.0679615757712823e-3f * (float)r, &sr_, &cr_);
    float s32, c32;
    sincosf(9.8174770424681038e-2f * (float)r, &s32, &c32);

    float gr[32], gi[32];
    float wr = 1.f, wi = 0.f;
    #pragma unroll
    for (int f = 0; f < 32; ++f) {
        float2 Fa = Fsh[rloc][f];
        float2 Fb = Fsh[rloc][f + 32];
        float wbr = wr * c32 - wi * s32;
        float wbi = wr * s32 + wi * c32;
        gr[f] = wr * Fa.x - wi * Fa.y + wbr * Fb.x - wbi * Fb.y;
        gi[f] = wr * Fa.y + wi * Fa.x + wbr * Fb.y + wbi * Fb.x;
        float t = wr * cr_ - wi * sr_;
        wi = wr * sr_ + wi * cr_;
        wr = t;
    }
    gr[0] -= 0.5f * Fsh[rloc][0].x;

    const float scl = 2.384185791015625e-7f;   // 2/(4096*2048)
    float* dst = out + ((size_t)(b * E + o) * H + h) * L + r;
    #pragma unroll
    for (int i = 0; i < 16; ++i) {
        float ae = 0.f, ao = 0.f;
        #pragma unroll
        for (int f = 0; f < 32; f += 2) {
            ae = fmaf(gr[f],      CS32[(f * i) & 31],       ae);
            ae = fmaf(gi[f],     -SN32[(f * i) & 31],       ae);
            ao = fmaf(gr[f + 1],  CS32[((f + 1) * i) & 31], ao);
            ao = fmaf(gi[f + 1], -SN32[((f + 1) * i) & 31], ao);
        }
        dst[64 * i]        = scl * (ae + ao);
        dst[64 * (i + 16)] = scl * (ae - ao);
    }
}

// ---------------------------------------------------------------------------
extern "C" void kernel_launch(void* const* d_in, const int* in_sizes, int n_in,
                              void* d_out, int out_size, void* d_ws, size_t ws_size,
                              hipStream_t stream)
{
    (void)in_sizes; (void)n_in; (void)out_size; (void)ws_size;
    const float* q    = (const float*)d_in[0];
    const float* k    = (const float*)d_in[1];
    // d_in[2] = v, unused by the reference
    const float* w_re = (const float*)d_in[3];
    const float* w_im = (const float*)d_in[4];
    float* out = (float*)d_out;

    // d_out scratch (dead before k_irfft): Xq [0,4M) Xk [4,8M) U [8,12M) Wt [16,32M)
    float2* Xq = (float2*)d_out;
    float2* Xk = Xq + PLANE;
    float2* Uu = Xk + PLANE;
    float2* Wt = (float2*)((char*)d_out + (size_t)16 * 1024 * 1024);
    // d_ws: R (4MB, survives) + Tg (8KB quarter table)
    float2* R  = (float2*)d_ws;
    float2* Tg = R + (size_t)PLANE;

    k_wtrans<<< 512, 256, 0, stream>>>(w_re, w_im, Wt, Tg);
    k_dft   <<<4096, 256, 0, stream>>>(q, k, Tg, Xq, Xk);
    k_mid   <<< 512, 256, 0, stream>>>(Xq, Xk, Uu);
    k_wmix  <<< 512, 256, 0, stream>>>(Uu, Wt, R);
    k_irfft <<<2048, 256, 0, stream>>>(R, out);
}

// Round 14
// 94.925 us; speedup vs baseline: 1.0859x; 1.0859x over previous
//
#include <hip/hip_runtime.h>
#include <math.h>

#define B 16
#define E 64
#define H 8
#define L 2048
#define M 64
#define PLANE (B*H*E*M)   // 524288 float2 per spectral plane

// exact 32-pt DFT twiddles: CS32[j]=cos(pi j/16), SN32[j]=sin(pi j/16)
constexpr float CS32[32] = {
     1.0f,                    0.9807852804032304f,   0.9238795325112868f,   0.8314696123025452f,
     0.7071067811865476f,     0.5555702330196022f,   0.3826834323650898f,   0.1950903220161283f,
     0.0f,                   -0.1950903220161283f,  -0.3826834323650898f,  -0.5555702330196022f,
    -0.7071067811865476f,    -0.8314696123025452f,  -0.9238795325112868f,  -0.9807852804032304f,
    -1.0f,                   -0.9807852804032304f,  -0.9238795325112868f,  -0.8314696123025452f,
    -0.7071067811865476f,    -0.5555702330196022f,  -0.3826834323650898f,  -0.1950903220161283f,
     0.0f,                    0.1950903220161283f,   0.3826834323650898f,   0.5555702330196022f,
     0.7071067811865476f,     0.8314696123025452f,   0.9238795325112868f,   0.9807852804032304f
};
constexpr float SN32[32] = {
     0.0f,                    0.1950903220161283f,   0.3826834323650898f,   0.5555702330196022f,
     0.7071067811865476f,     0.8314696123025452f,   0.9238795325112868f,   0.9807852804032304f,
     1.0f,                    0.9807852804032304f,   0.9238795325112868f,   0.8314696123025452f,
     0.7071067811865476f,     0.5555702330196022f,   0.3826834323650898f,   0.1950903220161283f,
     0.0f,                   -0.1950903220161283f,  -0.3826834323650898f,  -0.5555702330196022f,
    -0.7071067811865476f,    -0.8314696123025452f,  -0.9238795325112868f,  -0.9807852804032304f,
    -1.0f,                   -0.9807852804032304f,  -0.9238795325112868f,  -0.8314696123025452f,
    -0.7071067811865476f,    -0.5555702330196022f,  -0.3826834323650898f,  -0.1950903220161283f
};

__device__ inline void ctanhf_stable(float x, float y, float& re, float& im) {
    float ax = fabsf(x);
    if (ax > 11.0f) { re = copysignf(1.0f, x); im = 0.0f; return; }
    float t    = tanf(y);
    float beta = 1.0f + t * t;
    float s    = sinhf(x);
    float rho  = sqrtf(1.0f + s * s);
    float den  = 1.0f + beta * s * s;
    re = (beta * rho * s) / den;
    im = t / den;
}

// ---------------------------------------------------------------------------
// Prep kernel: W transpose (all 512 blocks) + twiddle tables (blocks 0..8).
// Wt: w_re/w_im [H][E][O][M] -> float2 [H][m][E][O].
// Tg[r*64+m] = e^{-i pi m r/1024} (r<32,m<64); Cg[j] = e^{-i pi j/32} (j<32).
// ---------------------------------------------------------------------------
__global__ __launch_bounds__(256) void k_wtrans(const float* __restrict__ wre,
                                                const float* __restrict__ wim,
                                                float2* __restrict__ Wt,
                                                float2* __restrict__ Tgo,
                                                float2* __restrict__ Cgo)
{
    __shared__ float tre[64][65], tim[64][65];
    int h  = blockIdx.x >> 6, rt = blockIdx.x & 63;
    int tid = threadIdx.x;

    // twiddle init (cheap tail work for the first 9 blocks)
    int gidx = blockIdx.x * 256 + tid;
    if (gidx < 2048) {
        int r = gidx >> 6, m = gidx & 63;
        double a = -3.14159265358979323846 * (double)(m * r) / 1024.0;
        Tgo[gidx] = make_float2((float)cos(a), (float)sin(a));
    } else if (gidx < 2080) {
        int j = gidx - 2048;
        double a = -3.14159265358979323846 * (double)j / 32.0;
        Cgo[j] = make_float2((float)cos(a), (float)sin(a));
    }

    int x = tid & 63, r4 = tid >> 6;
    const size_t base = ((size_t)h * 4096 + (size_t)rt * 64) * 64;
    #pragma unroll
    for (int j = 0; j < 16; ++j) {
        int row = j * 4 + r4;
        tre[row][x] = wre[base + (size_t)row * 64 + x];
        tim[row][x] = wim[base + (size_t)row * 64 + x];
    }
    __syncthreads();

    int row = tid & 63, x4 = tid >> 6;
    #pragma unroll
    for (int j = 0; j < 16; ++j) {
        int xx = j * 4 + x4;
        Wt[((size_t)h * 64 + xx) * 4096 + (size_t)rt * 64 + row] =
            make_float2(tre[row][xx], tim[row][xx]);
    }
}

// ---------------------------------------------------------------------------
// Forward DFT (measured best: ~60 us), 4 rows/block, wave-independent.
// One barrier (table staging). Phase 1: lane r: 32-pt real DFT -> Ysh[wave].
// Phase 2: lane (half,mlow): partial X[mlow], X[mlow+32] over its r-half via
// [32][64] twiddle table; half-1 post-rotates by +-Cg; combine via shfl.
// Structural note: feed/latency-bound. Falsified alternatives: load batching
// (r5), persistence+prefetch (r9), float4+LDS deinterleave (r11), 4 blocks/CU
// via 40KB LDS (r13, VALU cost exceeded occupancy gain). Keep as-is.
// ---------------------------------------------------------------------------
__global__ __launch_bounds__(256) void k_dft(const float* __restrict__ q,
                                             const float* __restrict__ k,
                                             const float2* __restrict__ Tg,
                                             const float2* __restrict__ Cgl,
                                             float2* __restrict__ Xq,
                                             float2* __restrict__ Xk)
{
    __shared__ float2 Ysh[4][64][17];   // 34,816 B (per-wave slices)
    __shared__ float2 Tsm[32][64];      // 16,384 B
    __shared__ float2 Cgs[32];          //    256 B  (total 51,456 B -> 3/CU)

    int tid  = threadIdx.x;
    int rloc = tid >> 6;
    int lane = tid & 63;
    int rid  = blockIdx.x * 4 + rloc;                  // 0..16383
    int tensor = rid >> 13;
    int r8 = rid & 8191;
    int b = r8 >> 9, h = (r8 >> 6) & 7, e = r8 & 63;

    #pragma unroll
    for (int j = 0; j < 8; ++j) ((float2*)Tsm)[tid + 256 * j] = Tg[tid + 256 * j];
    if (tid < 32) Cgs[tid] = Cgl[tid];
    __syncthreads();

    const float* src = (tensor ? k : q) + (((size_t)(b * E + e) * H + h) * L) + lane;
    float xs[32];
    #pragma unroll
    for (int i = 0; i < 32; ++i) xs[i] = src[i * 64];

    float s_[16], d_[16];
    #pragma unroll
    for (int i = 1; i <= 15; ++i) { s_[i] = xs[i] + xs[32 - i]; d_[i] = xs[i] - xs[32 - i]; }

    #pragma unroll
    for (int f = 0; f <= 16; ++f) {
        float ar = xs[0] + ((f & 1) ? -xs[16] : xs[16]);
        float ai = 0.f;
        #pragma unroll
        for (int i = 1; i <= 15; ++i) {
            ar = fmaf(s_[i], CS32[(f * i) & 31], ar);
            ai = fmaf(d_[i], SN32[(f * i) & 31], ai);
        }
        Ysh[rloc][lane][f] = make_float2(ar, -ai);
    }

    int mlow = lane & 31;
    int half = lane >> 5;
    int fi   = (mlow <= 16) ? mlow : 32 - mlow;
    float sgn = (mlow <= 16) ? 1.f : -1.f;

    float ar0 = 0.f, ai0 = 0.f, ar1 = 0.f, ai1 = 0.f;
    int rbase = half * 32;
    #pragma unroll
    for (int rb = 0; rb < 4; ++rb) {
        float2 tb[8], t2[8], yb[8];
        #pragma unroll
        for (int j = 0; j < 8; ++j) {
            int rp = rb * 8 + j;
            tb[j] = Tsm[rp][mlow];
            t2[j] = Tsm[rp][mlow + 32];
            yb[j] = Ysh[rloc][rbase + rp][fi];
        }
        #pragma unroll
        for (int j = 0; j < 8; ++j) {
            float yr = yb[j].x, yi = sgn * yb[j].y;
            ar0 = fmaf(yr, tb[j].x, ar0); ar0 = fmaf(-yi, tb[j].y, ar0);
            ai0 = fmaf(yr, tb[j].y, ai0); ai0 = fmaf(yi, tb[j].x, ai0);
            ar1 = fmaf(yr, t2[j].x, ar1); ar1 = fmaf(-yi, t2[j].y, ar1);
            ai1 = fmaf(yr, t2[j].y, ai1); ai1 = fmaf(yi, t2[j].x, ai1);
        }
    }

    if (half) {
        float2 c = Cgs[mlow];
        float t;
        t   = ar0 * c.x - ai0 * c.y;
        ai0 = ar0 * c.y + ai0 * c.x;  ar0 = t;
        t   = ar1 * c.x - ai1 * c.y;
        ai1 = ar1 * c.y + ai1 * c.x;  ar1 = t;
        ar1 = -ar1; ai1 = -ai1;
    }
    ar0 += __shfl_xor(ar0, 32);  ai0 += __shfl_xor(ai0, 32);
    ar1 += __shfl_xor(ar1, 32);  ai1 += __shfl_xor(ai1, 32);

    float2* dst = (tensor ? Xk : Xq) + ((size_t)(b * H + h) * E + e) * M;
    if (!half) dst[mlow]      = make_float2(ar0, ai0);
    else       dst[mlow + 32] = make_float2(ar1, ai1);
}

// ---------------------------------------------------------------------------
// Per (bh, x-quarter): S = tanh(Q^T K) (fp32 accum), then
// U[h][x][b][e] = sum_y S[x][y] K[e][y].  Grid 512 -> 2 blocks/CU.
// ---------------------------------------------------------------------------
__global__ __launch_bounds__(256) void k_mid(const float2* __restrict__ Xq,
                                             const float2* __restrict__ Xk,
                                             float2* __restrict__ U)
{
    __shared__ float Qre[64][16], Qim[64][16];   // [e][xl]; becomes S [y][xl]
    __shared__ float Kre[64][65], Kim[64][65];   // [e][m], padded

    int bh = blockIdx.x >> 2;
    int xh = (blockIdx.x & 3) * 16;
    int b  = bh >> 3, h = bh & 7;
    int tid = threadIdx.x;
    const float2* xq = Xq + (size_t)bh * 4096;
    const float2* xk = Xk + (size_t)bh * 4096;

    #pragma unroll
    for (int j = 0; j < 4; ++j) {
        int idx = tid + 256 * j;                 // 1024 = 64e * 16x
        int e = idx >> 4, xl = idx & 15;
        float2 v = xq[(e << 6) + xh + xl];
        Qre[e][xl] = v.x; Qim[e][xl] = v.y;
    }
    #pragma unroll
    for (int j = 0; j < 16; ++j) {
        int idx = tid + 256 * j;                 // 4096 = 64e * 64m
        int e = idx >> 6, mm = idx & 63;
        float2 v = xk[idx];
        Kre[e][mm] = v.x; Kim[e][mm] = v.y;
    }
    __syncthreads();

    int x  = tid & 15;
    int y0 = (tid >> 4) * 4;
    float ar[4], ai[4];
    #pragma unroll
    for (int j = 0; j < 4; ++j) { ar[j] = 0.f; ai[j] = 0.f; }

    for (int e = 0; e < 64; ++e) {
        float qr = Qre[e][x], qi = Qim[e][x];
        #pragma unroll
        for (int j = 0; j < 4; ++j) {
            float kr = Kre[e][y0 + j], ki = Kim[e][y0 + j];
            ar[j] = fmaf(qr, kr, ar[j]); ar[j] = fmaf(-qi, ki, ar[j]);
            ai[j] = fmaf(qr, ki, ai[j]); ai[j] = fmaf( qi, kr, ai[j]);
        }
    }
    float trj[4], tij[4];
    #pragma unroll
    for (int j = 0; j < 4; ++j) ctanhf_stable(ar[j], ai[j], trj[j], tij[j]);

    __syncthreads();
    #pragma unroll
    for (int j = 0; j < 4; ++j) { Qre[y0 + j][x] = trj[j]; Qim[y0 + j][x] = tij[j]; }
    __syncthreads();

    int eL    = tid & 63;
    int xslot = tid >> 6;                        // 0..3
    float ur[4], ui[4];
    #pragma unroll
    for (int j = 0; j < 4; ++j) { ur[j] = 0.f; ui[j] = 0.f; }

    for (int y = 0; y < 64; ++y) {
        float kr = Kre[eL][y], ki = Kim[eL][y];
        #pragma unroll
        for (int xp = 0; xp < 4; ++xp) {
            int xx = xp * 4 + xslot;
            float sr = Qre[y][xx], si = Qim[y][xx];
            ur[xp] += sr * kr - si * ki;
            ui[xp] += sr * ki + si * kr;
        }
    }
    #pragma unroll
    for (int xp = 0; xp < 4; ++xp) {
        int xx = xp * 4 + xslot;
        U[(((size_t)h * 64 + xh + xx) * 16 + b) * 64 + eL] = make_float2(ur[xp], ui[xp]);
    }
}

// ---------------------------------------------------------------------------
// Per (h, mode x): R[b][o] = sum_e U[b][e] * Wt[e][o]
// ---------------------------------------------------------------------------
__global__ __launch_bounds__(256) void k_wmix(const float2* __restrict__ U,   // [h][x][b][e]
                                              const float2* __restrict__ Wt,  // [h][x][e][o]
                                              float2* __restrict__ R)
{
    __shared__ float2 Usm[16][64];
    __shared__ float2 Wsm[64][64];

    int h = blockIdx.x >> 6, x = blockIdx.x & 63;
    int tid = threadIdx.x;

    const float2* usrc = U  + ((size_t)h * 64 + x) * 1024;
    #pragma unroll
    for (int j = 0; j < 4; ++j) {
        int idx = tid + 256 * j;
        ((float2*)Usm)[idx] = usrc[idx];
    }
    const float2* wsrc = Wt + ((size_t)h * 64 + x) * 4096;
    #pragma unroll
    for (int j = 0; j < 16; ++j) {
        int idx = tid + 256 * j;
        ((float2*)Wsm)[idx] = wsrc[idx];
    }
    __syncthreads();

    int o = tid & 63, b0 = tid >> 6;
    float rr[4], ri[4];
    #pragma unroll
    for (int j = 0; j < 4; ++j) { rr[j] = 0.f; ri[j] = 0.f; }

    for (int e = 0; e < 64; ++e) {
        float2 w = Wsm[e][o];
        #pragma unroll
        for (int j = 0; j < 4; ++j) {
            float2 u = Usm[b0 + 4 * j][e];
            rr[j] += u.x * w.x - u.y * w.y;
            ri[j] += u.x * w.y + u.y * w.x;
        }
    }
    #pragma unroll
    for (int j = 0; j < 4; ++j) {
        int b = b0 + 4 * j;
        R[((size_t)(b * H + h) * 64 + o) * 64 + x] = make_float2(rr[j], ri[j]);
    }
}

// ---------------------------------------------------------------------------
// irFFT, 4 rows per block, barrier-free (Fsh exchange is intra-wave).
// ---------------------------------------------------------------------------
__global__ __launch_bounds__(256) void k_irfft(const float2* __restrict__ R,
                                               float* __restrict__ out)
{
    __shared__ float2 Fsh[4][64];
    int rloc = threadIdx.x >> 6;
    int r    = threadIdx.x & 63;
    int bho  = blockIdx.x * 4 + rloc;
    int o  = bho & 63, bh = bho >> 6;
    int h  = bh & 7,   b  = bh >> 3;

    Fsh[rloc][r] = R[(size_t)bho * 64 + r];   // wave-private row; no barrier

    float sr_, cr_;
    sincosf(3.0679615757712823e-3f * (float)r, &sr_, &cr_);
    float s32, c32;
    sincosf(9.8174770424681038e-2f * (float)r, &s32, &c32);

    float gr[32], gi[32];
    float wr = 1.f, wi = 0.f;
    #pragma unroll
    for (int f = 0; f < 32; ++f) {
        float2 Fa = Fsh[rloc][f];
        float2 Fb = Fsh[rloc][f + 32];
        float wbr = wr * c32 - wi * s32;
        float wbi = wr * s32 + wi * c32;
        gr[f] = wr * Fa.x - wi * Fa.y + wbr * Fb.x - wbi * Fb.y;
        gi[f] = wr * Fa.y + wi * Fa.x + wbr * Fb.y + wbi * Fb.x;
        float t = wr * cr_ - wi * sr_;
        wi = wr * sr_ + wi * cr_;
        wr = t;
    }
    gr[0] -= 0.5f * Fsh[rloc][0].x;

    const float scl = 2.384185791015625e-7f;   // 2/(4096*2048)
    float* dst = out + ((size_t)(b * E + o) * H + h) * L + r;
    #pragma unroll
    for (int i = 0; i < 16; ++i) {
        float ae = 0.f, ao = 0.f;
        #pragma unroll
        for (int f = 0; f < 32; f += 2) {
            ae = fmaf(gr[f],      CS32[(f * i) & 31],       ae);
            ae = fmaf(gi[f],     -SN32[(f * i) & 31],       ae);
            ao = fmaf(gr[f + 1],  CS32[((f + 1) * i) & 31], ao);
            ao = fmaf(gi[f + 1], -SN32[((f + 1) * i) & 31], ao);
        }
        dst[64 * i]        = scl * (ae + ao);
        dst[64 * (i + 16)] = scl * (ae - ao);
    }
}

// ---------------------------------------------------------------------------
extern "C" void kernel_launch(void* const* d_in, const int* in_sizes, int n_in,
                              void* d_out, int out_size, void* d_ws, size_t ws_size,
                              hipStream_t stream)
{
    (void)in_sizes; (void)n_in; (void)out_size; (void)ws_size;
    const float* q    = (const float*)d_in[0];
    const float* k    = (const float*)d_in[1];
    // d_in[2] = v, unused by the reference
    const float* w_re = (const float*)d_in[3];
    const float* w_im = (const float*)d_in[4];
    float* out = (float*)d_out;

    // d_out scratch (dead before k_irfft): Xq [0,4M) Xk [4,8M) U [8,12M) Wt [16,32M)
    float2* Xq = (float2*)d_out;
    float2* Xk = Xq + PLANE;
    float2* Uu = Xk + PLANE;
    float2* Wt = (float2*)((char*)d_out + (size_t)16 * 1024 * 1024);
    // d_ws: R (4MB, survives) + Tg (16KB) + Cg (256B)
    float2* R  = (float2*)d_ws;
    float2* Tg = R + (size_t)PLANE;
    float2* Cg = Tg + 2048;

    k_wtrans<<< 512, 256, 0, stream>>>(w_re, w_im, Wt, Tg, Cg);
    k_dft   <<<4096, 256, 0, stream>>>(q, k, Tg, Cg, Xq, Xk);
    k_mid   <<< 512, 256, 0, stream>>>(Xq, Xk, Uu);
    k_wmix  <<< 512, 256, 0, stream>>>(Uu, Wt, R);
    k_irfft <<<2048, 256, 0, stream>>>(R, out);
}